// Round 11
// baseline (73.487 us; speedup 1.0000x reference)
//
#include <hip/hip_runtime.h>
#include <cstddef>
#include <cmath>

#define BN 2
#define CH 48
#define HW 4096
#define NH 3
#define QC 144      // 3*CH
#define RR 3        // CH/16
#define KSPLIT 4
#define NPLANE 17   // 16 acc + 1 denom planes per (ks,bh)
#define LOG2E 1.4426950408889634f

typedef __attribute__((ext_vector_type(8))) short bf16x8;
typedef __attribute__((ext_vector_type(16))) float f32x16;
typedef __attribute__((ext_vector_type(4))) float f32x4;

// ---- workspace layout (floats) ----
constexpr size_t OFF_BP  = 0;                       // 128*48 = 6144 (b*64+row rows)
constexpr size_t OFF_QB  = 12288;                   // 98304 (bf16 [bh][n][16])
constexpr size_t OFF_KB  = OFF_QB + 98304;
constexpr size_t OFF_VT  = OFF_KB + 98304;
constexpr size_t OFF_QKV1= OFF_VT + 98304;          // (unused now)
constexpr size_t OFF_PART= OFF_QKV1 + 1179648;      // 4*6*17*4096 = 1671168

static __device__ __forceinline__ unsigned cvtpk(float lo, float hi) {
  unsigned r;
  asm("v_cvt_pk_bf16_f32 %0, %1, %2" : "=v"(r) : "v"(lo), "v"(hi));
  return r;
}

static __device__ __forceinline__ float fexp2(float x) {
#if __has_builtin(__builtin_amdgcn_exp2f)
  return __builtin_amdgcn_exp2f(x);
#else
  float r; asm("v_exp_f32 %0, %1" : "=v"(r) : "v"(x)); return r;
#endif
}

// ---------- K1: fused LN1 + conv1x1 + depthwise3x3 + token norm/pack ----------
// Block = (bh, image row), 512 thr (8 grps x 64 px). Recomputes LN+conv for the
// 3 stencil rows in LDS (row-at-a-time xt1), so qkv1 never touches HBM.
// OOB halo rows are zeroed in qt (SAME-pad contributes 0 -> exact).
__global__ __launch_bounds__(512) void k_front(const float* __restrict__ x,
                                               const float* __restrict__ lw,
                                               const float* __restrict__ lb,
                                               const float* __restrict__ w,
                                               const float* __restrict__ bias,
                                               const float* __restrict__ dww,
                                               const float* __restrict__ dwb,
                                               const float* __restrict__ temp,
                                               ushort* __restrict__ Qb,
                                               ushort* __restrict__ Kb,
                                               ushort* __restrict__ Vtb,
                                               float* __restrict__ bpool) {
  __shared__ float xt1[CH][64];          // LN output, one row at a time
  __shared__ float qt[3][CH][64];        // conv1x1 outputs (oc = which*16+cc)
  __shared__ float red1[8][64], red2[8][64];
  int blk = blockIdx.x;                  // bh*64 + row
  int row = blk & 63, bh = blk >> 6;
  int b = bh / NH, h = bh % NH;
  int t = threadIdx.x;
  int px = t & 63, grp = t >> 6;         // grp 0..7

  for (int r = 0; r < 3; ++r) {
    int yy = row + r - 1;
    if (yy < 0 || yy >= 64) {            // block-uniform branch
      for (int i = t; i < CH*64; i += 512) (&qt[r][0][0])[i] = 0.f;
      __syncthreads();
      continue;
    }
    // LN phase: grp loads 6 channels of this row
    const float* xb = x + (size_t)b*CH*HW + yy*64 + px;
    float v[6]; float s = 0.f, ss = 0.f;
#pragma unroll
    for (int j = 0; j < 6; ++j) {
      float vv = xb[(size_t)(grp*6 + j)*HW];
      v[j] = vv; s += vv; ss += vv*vv;
    }
    red1[grp][px] = s; red2[grp][px] = ss;
    __syncthreads();
    float stot = 0.f, sstot = 0.f;
#pragma unroll
    for (int i = 0; i < 8; ++i) { stot += red1[i][px]; sstot += red2[i][px]; }
    float mu = stot * (1.f/CH);
    float rs = rsqrtf(sstot*(1.f/CH) - mu*mu + 1e-6f);
#pragma unroll
    for (int j = 0; j < 6; ++j) {
      int c = grp*6 + j;
      xt1[c][px] = lw[c]*((v[j]-mu)*rs) + lb[c];
    }
    __syncthreads();
    // per-row pool partial (only h==0 blocks, center row)
    if (r == 1 && h == 0 && t < CH) {
      float a = 0.f;
#pragma unroll
      for (int p2 = 0; p2 < 64; ++p2) a += xt1[t][p2];
      bpool[(size_t)(b*64 + row)*CH + t] = a;
    }
    // conv phase: grp computes oc = grp*6..+5 (oc = which*16+cc local layout)
    float xv[CH];
#pragma unroll
    for (int ci = 0; ci < CH; ++ci) xv[ci] = xt1[ci][px];
#pragma unroll
    for (int oi = 0; oi < 6; ++oi) {
      int oc = grp*6 + oi;
      int c = (oc >> 4)*48 + h*16 + (oc & 15);
      float a = bias[c];
#pragma unroll
      for (int ci = 0; ci < CH; ++ci) a += w[(size_t)c*CH + ci]*xv[ci];
      qt[r][oc][px] = a;
    }
    __syncthreads();
  }

  // depthwise 3x3 (rows all in LDS) + norms + pack
  int n = row*64 + px;
  float q[2], k[2], vv2[2];
  float sq = 0.f, sk = 0.f;
#pragma unroll
  for (int j = 0; j < 2; ++j) {
    int cc = grp*2 + j;
#pragma unroll
    for (int which = 0; which < 3; ++which) {
      int oc = which*16 + cc;
      int cg = which*48 + h*16 + cc;
      const float* wc = dww + (size_t)cg*9;
      float a = dwb[cg];
#pragma unroll
      for (int rr = 0; rr < 3; ++rr) {
#pragma unroll
        for (int dx = 0; dx < 3; ++dx) {
          int xx = px + dx - 1;
          float tv = (xx >= 0 && xx < 64) ? qt[rr][oc][xx] : 0.f;
          a += wc[rr*3 + dx] * tv;
        }
      }
      if (which == 0)      { q[j] = a;  sq += a*a; }
      else if (which == 1) { k[j] = a;  sk += a*a; }
      else                 vv2[j] = a;
    }
  }
  red1[grp][px] = sq; red2[grp][px] = sk;
  __syncthreads();
  float tsq = 0.f, tsk = 0.f;
#pragma unroll
  for (int i = 0; i < 8; ++i) { tsq += red1[i][px]; tsk += red2[i][px]; }
  float tq = temp[h] * LOG2E / fmaxf(sqrtf(tsq), 1e-12f);
  float ik = 1.f            / fmaxf(sqrtf(tsk), 1e-12f);
  *(uint*)(Qb + ((size_t)bh*HW + n)*16 + grp*2) = cvtpk(q[0]*tq, q[1]*tq);
  *(uint*)(Kb + ((size_t)bh*HW + n)*16 + grp*2) = cvtpk(k[0]*ik, k[1]*ik);
  Vtb[((size_t)bh*16 + grp*2    )*HW + n] = (ushort)(cvtpk(vv2[0], vv2[0]) & 0xffffu);
  Vtb[((size_t)bh*16 + grp*2 + 1)*HW + n] = (ushort)(cvtpk(vv2[1], vv2[1]) & 0xffffu);
}

// ---------- K2: MFMA flash attention: skewed LDS pipeline + K/V global prefetch ----------
#define PACK(stv, wbp) do {                                              \
  _Pragma("unroll")                                                      \
  for (int g4 = 0; g4 < 4; ++g4) {                                       \
    float e0 = fmaxf(fexp2((stv)[4*g4+0]), 1.f);                         \
    float e1 = fmaxf(fexp2((stv)[4*g4+1]), 1.f);                         \
    float e2 = fmaxf(fexp2((stv)[4*g4+2]), 1.f);                         \
    float e3 = fmaxf(fexp2((stv)[4*g4+3]), 1.f);                         \
    uint2 pk;                                                            \
    pk.x = cvtpk(e0, e1);                                                \
    pk.y = cvtpk(e2, e3);                                                \
    *(uint2*)((wbp) + wroff + 16*(g4 ^ sw)) = pk;                        \
  } } while (0)

__global__ __launch_bounds__(256) void k_attn(const ushort* __restrict__ Qb,
                                              const ushort* __restrict__ Kb,
                                              const ushort* __restrict__ Vtb,
                                              float* __restrict__ part) {
  __shared__ char smem[4][4096];       // per-wave slice
  int blk = blockIdx.x;                // bh(6) x qt(32) x ks(4)
  int ks = blk & (KSPLIT-1);
  int qt = (blk >> 2) & 31;
  int bh = blk >> 7;
  int lane = threadIdx.x & 63;
  int wid  = threadIdx.x >> 6;
  int l31 = lane & 31;
  int lhi = lane >> 5;
  int qbase = qt*128 + wid*32;

  bf16x8 qf = *(const bf16x8*)(Qb + ((size_t)bh*HW + qbase + l31)*16 + lhi*8);

  const f32x16 z16 = {0,0,0,0,0,0,0,0,0,0,0,0,0,0,0,0};
  const short oneb = (short)0x3f80;
  const bf16x8 ones = {oneb,oneb,oneb,oneb,oneb,oneb,oneb,oneb};
  f32x4 acc0 = {0,0,0,0}, acc1 = {0,0,0,0};
  f32x4 accD0 = {0,0,0,0}, accD1 = {0,0,0,0};
  char* base = &smem[wid][0];
  int qr = lane & 15, gr = lane >> 4;
  int rdoff0 = qr*64 + 16*(gr ^ ((qr>>1)&3));
  int sw = (l31 >> 1) & 3;
  int wroff = l31*64 + 8*lhi;

  const ushort* Kbase = Kb + (size_t)bh*HW*16;
  const ushort* Vbase = Vtb + ((size_t)bh*16 + qr)*HW;
  int kbeg = ks * (HW/KSPLIT);
  constexpr int ITERS = (HW/KSPLIT)/32;   // 32

  // prologue: S(0) -> buf0; prefetch K(1) and V(0)
  bf16x8 kf = *(const bf16x8*)(Kbase + (size_t)(kbeg + l31)*16 + lhi*8);
  f32x16 st = __builtin_amdgcn_mfma_f32_32x32x16_bf16(kf, qf, z16, 0, 0, 0);
  bf16x8 kfn = *(const bf16x8*)(Kbase + (size_t)(kbeg + 32 + l31)*16 + lhi*8);
  bf16x8 vfn = *(const bf16x8*)(Vbase + kbeg + 8*gr);
  PACK(st, base);

#pragma unroll 4
  for (int i = 1; i < ITERS; ++i) {
    char* rb = base + ((i-1) & 1)*2048;
    bf16x8 pa0 = *(const bf16x8*)(rb + rdoff0);
    bf16x8 pa1 = *(const bf16x8*)(rb + 1024 + rdoff0);
    f32x16 stn = __builtin_amdgcn_mfma_f32_32x32x16_bf16(kfn, qf, z16, 0, 0, 0);
    // prefetch K(i+1); at i=ITERS-1 reads adjacent ws region, never consumed.
    kfn = *(const bf16x8*)(Kbase + (size_t)(kbeg + (i+1)*32 + l31)*16 + lhi*8);
    bf16x8 vf = vfn;
    vfn = *(const bf16x8*)(Vbase + kbeg + i*32 + 8*gr);   // V(i) for next iter
    acc0  = __builtin_amdgcn_mfma_f32_16x16x32_bf16(pa0, vf, acc0, 0, 0, 0);
    acc1  = __builtin_amdgcn_mfma_f32_16x16x32_bf16(pa1, vf, acc1, 0, 0, 0);
    accD0 = __builtin_amdgcn_mfma_f32_16x16x32_bf16(pa0, ones, accD0, 0, 0, 0);
    accD1 = __builtin_amdgcn_mfma_f32_16x16x32_bf16(pa1, ones, accD1, 0, 0, 0);
    PACK(stn, base + (i & 1)*2048);
  }
  {
    char* rb = base + ((ITERS-1) & 1)*2048;
    bf16x8 pa0 = *(const bf16x8*)(rb + rdoff0);
    bf16x8 pa1 = *(const bf16x8*)(rb + 1024 + rdoff0);
    acc0  = __builtin_amdgcn_mfma_f32_16x16x32_bf16(pa0, vfn, acc0, 0, 0, 0);
    acc1  = __builtin_amdgcn_mfma_f32_16x16x32_bf16(pa1, vfn, acc1, 0, 0, 0);
    accD0 = __builtin_amdgcn_mfma_f32_16x16x32_bf16(pa0, ones, accD0, 0, 0, 0);
    accD1 = __builtin_amdgcn_mfma_f32_16x16x32_bf16(pa1, ones, accD1, 0, 0, 0);
  }

  // epilogue overlay: ep[slot][q] f32 in the wave's own slice
  float* ep = (float*)base;
#pragma unroll
  for (int r = 0; r < 4; ++r) {
    ep[qr*32 + gr*4 + r]      = acc0[r];
    ep[qr*32 + gr*4 + 16 + r] = acc1[r];
  }
  if (qr == 0) {
#pragma unroll
    for (int r = 0; r < 4; ++r) {
      ep[16*32 + gr*4 + r]      = accD0[r];
      ep[16*32 + gr*4 + 16 + r] = accD1[r];
    }
  }
  __syncthreads();
  size_t pb = ((size_t)(ks*6 + bh))*NPLANE;
  for (int i = threadIdx.x; i < 4*32*NPLANE; i += 256) {
    int w = i / (32*NPLANE);
    int rem = i - w*(32*NPLANE);
    int cc = rem >> 5;
    int q = rem & 31;
    part[(pb + cc)*HW + qt*128 + w*32 + q] = ((float*)&smem[w][0])[cc*32 + q];
  }
}

// ---------- K3: tail — SE + ksplit-reduce + combine + LN2 + full FFN ----------
// 256 blocks x 384 thr; 32-px tiles; 12 groups of 32 lanes, 4 channels each.
__global__ __launch_bounds__(384) void k_tail(const float* __restrict__ part,
                                              const float* __restrict__ x,
                                              const float* __restrict__ lw1,
                                              const float* __restrict__ lb1,
                                              const float* __restrict__ bpool,
                                              const float* __restrict__ w1,
                                              const float* __restrict__ b1,
                                              const float* __restrict__ w2,
                                              const float* __restrict__ b2,
                                              const float* __restrict__ beta,
                                              const float* __restrict__ beta2,
                                              const float* __restrict__ lw2,
                                              const float* __restrict__ lb2,
                                              const float* __restrict__ w4,
                                              const float* __restrict__ b4,
                                              const float* __restrict__ w5,
                                              const float* __restrict__ b5,
                                              const float* __restrict__ gamma,
                                              float* __restrict__ out) {
  __shared__ float sepm[CH][4];
  __shared__ float pmL[CH];
  __shared__ float yrL[4];
  __shared__ float seL[CH];
  __shared__ float r1[12][32], r2[12][32], r3[12][32], r4[12][32];
  __shared__ float xt[CH][33];   // LN2 output
  __shared__ float gt[CH][33];   // gate output
  int t = threadIdx.x;
  int px = t & 31, g12 = t >> 5;      // 12 groups
  int h = g12 >> 2;
  int c0 = g12 * 4;
  int qoff = (g12 & 3) * 4;
  int gp = blockIdx.x*32 + px;
  int b = gp >> 12, n = gp & 4095;
  int bh = b*NH + h;

  // SE MLP (block-redundant; bpool is L2-hot; 64 row-partials per b)
  if (t < 192) {
    int c = t % CH, j = t / CH;       // j 0..3
    const float* bp = bpool + (size_t)(b*64 + j*16)*CH + c;
    float a = 0.f;
#pragma unroll
    for (int i = 0; i < 16; ++i) a += bp[(size_t)i*CH];
    sepm[c][j] = a;
  }
  __syncthreads();
  if (t < CH) pmL[t] = (sepm[t][0]+sepm[t][1]+sepm[t][2]+sepm[t][3]) * (1.f/HW);
  __syncthreads();
  if (t < RR) {
    float a = b1[t];
    for (int c = 0; c < CH; ++c) a += w1[t*CH+c]*pmL[c];
    yrL[t] = fmaxf(a, 0.f);
  }
  __syncthreads();
  if (t < CH) {
    float a = b2[t];
    for (int r = 0; r < RR; ++r) a += w2[t*RR+r]*yrL[r];
    seL[t] = 1.f/(1.f+__expf(-a));
  }

  // ksplit reduce: 4 channels + den per thread
  float acc[4] = {0,0,0,0};
  float den = 0.f;
#pragma unroll
  for (int ks = 0; ks < KSPLIT; ++ks) {
    const float* pl = part + ((size_t)((ks*6+bh)*NPLANE + qoff))*HW + n;
#pragma unroll
    for (int cc = 0; cc < 4; ++cc) acc[cc] += pl[(size_t)cc*HW];
    den += pl[(size_t)(16 - qoff)*HW];
  }
  // LN1 stats on x
  const float* xp = x + ((size_t)b*CH + c0)*HW + n;
  float xv[4]; float s = 0.f, ssum = 0.f;
#pragma unroll
  for (int cc = 0; cc < 4; ++cc) {
    float vv = xp[(size_t)cc*HW];
    xv[cc] = vv; s += vv; ssum += vv*vv;
  }
  r1[g12][px] = s; r2[g12][px] = ssum;
  __syncthreads();
  float stot = 0.f, sstot = 0.f;
#pragma unroll
  for (int i = 0; i < 12; ++i) { stot += r1[i][px]; sstot += r2[i][px]; }
  float mu = stot*(1.f/CH);
  float rs = rsqrtf(sstot*(1.f/CH) - mu*mu + 1e-6f);
  float inv = 1.f / den;
  float yv[4]; float s2 = 0.f, ss2 = 0.f;
#pragma unroll
  for (int cc = 0; cc < 4; ++cc) {
    int c = c0 + cc;
    float xnv = lw1[c]*((xv[cc]-mu)*rs) + lb1[c];
    float y = xv[cc] + xnv*seL[c]*beta[c] + acc[cc]*inv*beta2[c];
    yv[cc] = y; s2 += y; ss2 += y*y;
  }
  r3[g12][px] = s2; r4[g12][px] = ss2;
  __syncthreads();
  float s2t = 0.f, ss2t = 0.f;
#pragma unroll
  for (int i = 0; i < 12; ++i) { s2t += r3[i][px]; ss2t += r4[i][px]; }
  float mu2 = s2t*(1.f/CH);
  float rs2 = rsqrtf(ss2t*(1.f/CH) - mu2*mu2 + 1e-6f);
#pragma unroll
  for (int cc = 0; cc < 4; ++cc) {
    int c = c0 + cc;
    xt[c][px] = lw2[c]*((yv[cc]-mu2)*rs2) + lb2[c];
  }
  __syncthreads();

  // conv4 + gate: group-uniform rows
  float f1[4], f2[4];
#pragma unroll
  for (int j = 0; j < 4; ++j) { f1[j] = b4[c0+j]; f2[j] = b4[CH+c0+j]; }
#pragma unroll 8
  for (int c = 0; c < CH; ++c) {
    float tc = xt[c][px];
#pragma unroll
    for (int j = 0; j < 4; ++j) {
      f1[j] += w4[(size_t)(c0+j)*CH + c] * tc;
      f2[j] += w4[(size_t)(CH+c0+j)*CH + c] * tc;
    }
  }
#pragma unroll
  for (int j = 0; j < 4; ++j) gt[c0+j][px] = f1[j]*f2[j];
  __syncthreads();

  // conv5 + residual
  float f5[4];
#pragma unroll
  for (int j = 0; j < 4; ++j) f5[j] = b5[c0+j];
#pragma unroll 8
  for (int c = 0; c < CH; ++c) {
    float gc = gt[c][px];
#pragma unroll
    for (int j = 0; j < 4; ++j) f5[j] += w5[(size_t)(c0+j)*CH + c] * gc;
  }
  float* op = out + ((size_t)b*CH + c0)*HW + n;
#pragma unroll
  for (int j = 0; j < 4; ++j)
    op[(size_t)j*HW] = yv[j] + f5[j]*gamma[c0+j];
}

extern "C" void kernel_launch(void* const* d_in, const int* in_sizes, int n_in,
                              void* d_out, int out_size, void* d_ws, size_t ws_size,
                              hipStream_t stream) {
  const float* x      = (const float*)d_in[0];
  const float* ln1_w  = (const float*)d_in[1];
  const float* ln1_b  = (const float*)d_in[2];
  const float* qkv_w  = (const float*)d_in[3];
  const float* qkv_b  = (const float*)d_in[4];
  const float* dw_w   = (const float*)d_in[5];
  const float* dw_b   = (const float*)d_in[6];
  const float* temp   = (const float*)d_in[7];
  const float* ca_w1  = (const float*)d_in[8];
  const float* ca_b1  = (const float*)d_in[9];
  const float* ca_w2  = (const float*)d_in[10];
  const float* ca_b2  = (const float*)d_in[11];
  const float* beta   = (const float*)d_in[12];
  const float* beta2  = (const float*)d_in[13];
  const float* ln2_w  = (const float*)d_in[14];
  const float* ln2_b  = (const float*)d_in[15];
  const float* conv4_w= (const float*)d_in[16];
  const float* conv4_b= (const float*)d_in[17];
  const float* conv5_w= (const float*)d_in[18];
  const float* conv5_b= (const float*)d_in[19];
  const float* gamma  = (const float*)d_in[20];

  float* ws   = (float*)d_ws;
  float* bp   = ws + OFF_BP;
  ushort* Qb  = (ushort*)(ws + OFF_QB);
  ushort* Kb  = (ushort*)(ws + OFF_KB);
  ushort* Vtb = (ushort*)(ws + OFF_VT);
  float* part = ws + OFF_PART;
  float* out  = (float*)d_out;

  k_front<<<384, 512, 0, stream>>>(x, ln1_w, ln1_b, qkv_w, qkv_b,
                                   dw_w, dw_b, temp, Qb, Kb, Vtb, bp);
  k_attn <<<768, 256, 0, stream>>>(Qb, Kb, Vtb, part);
  k_tail <<<256, 384, 0, stream>>>(part, x, ln1_w, ln1_b, bp,
                                   ca_w1, ca_b1, ca_w2, ca_b2,
                                   beta, beta2, ln2_w, ln2_b,
                                   conv4_w, conv4_b, conv5_w, conv5_b,
                                   gamma, out);
}

// Round 12
// 57.201 us; speedup vs baseline: 1.2847x; 1.2847x over previous
//
#include <hip/hip_runtime.h>
#include <cstddef>
#include <cmath>

#define BN 2
#define CH 48
#define HW 4096
#define NH 3
#define QC 144      // 3*CH
#define RR 3        // CH/16
#define KSPLIT 4
#define NPLANE 17   // 16 acc + 1 denom planes per (ks,bh)
#define LOG2E 1.4426950408889634f

typedef __attribute__((ext_vector_type(8))) short bf16x8;
typedef __attribute__((ext_vector_type(16))) float f32x16;
typedef __attribute__((ext_vector_type(4))) float f32x4;

// ---- workspace layout (floats) ----
constexpr size_t OFF_BP  = 0;                       // 128*48 rows (b*64+tile)
constexpr size_t OFF_QB  = 12288;                   // 98304 (bf16 [bh][n][16])
constexpr size_t OFF_KB  = OFF_QB + 98304;
constexpr size_t OFF_VT  = OFF_KB + 98304;
constexpr size_t OFF_QKV1= OFF_VT + 98304;          // 1179648
constexpr size_t OFF_PART= OFF_QKV1 + 1179648;      // 4*6*17*4096 = 1671168

static __device__ __forceinline__ unsigned cvtpk(float lo, float hi) {
  unsigned r;
  asm("v_cvt_pk_bf16_f32 %0, %1, %2" : "=v"(r) : "v"(lo), "v"(hi));
  return r;
}

static __device__ __forceinline__ float fexp2(float x) {
#if __has_builtin(__builtin_amdgcn_exp2f)
  return __builtin_amdgcn_exp2f(x);
#else
  float r; asm("v_exp_f32 %0, %1" : "=v"(r) : "v"(x)); return r;
#endif
}

// ---------- K1: fused LN1 + pool-partial + conv1x1(48->144) ----------
// 512 thr = 8 waves; wave = one 64-lane channel-group (weights via SGPR s_load
// after readfirstlane). 64-px tiles; grid b(2) x tile(64) x oh(2) = 256.
__global__ __launch_bounds__(512) void k_lnconv(const float* __restrict__ x,
                                                const float* __restrict__ lw,
                                                const float* __restrict__ lb,
                                                const float* __restrict__ w,
                                                const float* __restrict__ bias,
                                                float* __restrict__ qkv1,
                                                float* __restrict__ bpool) {
  __shared__ float xt[CH][64];
  __shared__ float red1[8][64], red2[8][64];
  int blk = blockIdx.x;          // b(1b? no) : oh = blk&1, tile = (blk>>1)&63, b = blk>>7
  int oh = blk & 1;
  int tile = (blk >> 1) & 63;
  int b = blk >> 7;
  int t = threadIdx.x;
  int px = t & 63, grp = t >> 6;   // 8 wave-groups of 6 channels
  int n0 = tile*64;
  const float* xb = x + (size_t)b*CH*HW + n0 + px;
  float v[6]; float s = 0.f, ss = 0.f;
#pragma unroll
  for (int j = 0; j < 6; ++j) {
    float vv = xb[(size_t)(grp*6 + j)*HW];
    v[j] = vv; s += vv; ss += vv*vv;
  }
  red1[grp][px] = s; red2[grp][px] = ss;
  __syncthreads();
  float stot = 0.f, sstot = 0.f;
#pragma unroll
  for (int i = 0; i < 8; ++i) { stot += red1[i][px]; sstot += red2[i][px]; }
  float mu = stot * (1.f/CH);
  float rs = rsqrtf(sstot*(1.f/CH) - mu*mu + 1e-6f);
#pragma unroll
  for (int j = 0; j < 6; ++j) {
    int c = grp*6 + j;
    xt[c][px] = lw[c]*((v[j]-mu)*rs) + lb[c];
  }
  __syncthreads();
  if (oh == 0 && t < CH) {
    float a = 0.f;
#pragma unroll
    for (int p2 = 0; p2 < 64; ++p2) a += xt[t][p2];
    bpool[(size_t)(b*64 + tile)*CH + t] = a;
  }
  float xv[CH];
#pragma unroll
  for (int c = 0; c < CH; ++c) xv[c] = xt[c][px];
  float* op = qkv1 + (size_t)b*QC*HW + n0 + px;
#pragma unroll 3
  for (int oi = 0; oi < 9; ++oi) {
    int o = __builtin_amdgcn_readfirstlane(grp*18 + oh*9 + oi);  // wave-uniform
    const float* wrow = w + (size_t)o*CH;
    float a = bias[o];
#pragma unroll
    for (int c = 0; c < CH; ++c) a += wrow[c]*xv[c];
    op[(size_t)o*HW] = a;
  }
}

// ---------- K2: fused depthwise3x3 + token norm/pack (8 waves, 2ch groups) ----------
__global__ __launch_bounds__(512) void k_dwprep(const float* __restrict__ qkv1,
                                                const float* __restrict__ dww,
                                                const float* __restrict__ dwb,
                                                const float* __restrict__ temp,
                                                ushort* __restrict__ Qb,
                                                ushort* __restrict__ Kb,
                                                ushort* __restrict__ Vtb) {
  __shared__ float sqq[8][64], sqk[8][64];
  int blk = blockIdx.x;               // bh*64 + row
  int row = blk & 63, bh = blk >> 6;
  int b = bh / NH, h = bh % NH;
  int px = threadIdx.x & 63, grp = threadIdx.x >> 6;   // grp 0..7, wave-uniform
  int n = row*64 + px;
  const float* base = qkv1 + (size_t)b*QC*HW;

  float q[2], k[2], v[2];
  float sq = 0.f, sk = 0.f;
#pragma unroll
  for (int j = 0; j < 2; ++j) {
#pragma unroll
    for (int which = 0; which < 3; ++which) {
      int c = __builtin_amdgcn_readfirstlane(which*48 + h*16 + grp*2 + j);
      const float* ip = base + (size_t)c*HW;
      const float* wc = dww + (size_t)c*9;
      float w0 = wc[0], w1 = wc[1], w2 = wc[2],
            w3 = wc[3], w4 = wc[4], w5 = wc[5],
            w6 = wc[6], w7 = wc[7], w8 = wc[8];
      float a = dwb[c];
#pragma unroll
      for (int dy = 0; dy < 3; ++dy) {
        int yy = row + dy - 1;
        if (yy < 0 || yy >= 64) continue;
        const float* rp = ip + yy*64;
        float wl = dy==0?w0:(dy==1?w3:w6);
        float wm = dy==0?w1:(dy==1?w4:w7);
        float wr = dy==0?w2:(dy==1?w5:w8);
        float tm = rp[px];
        float tl = (px >= 1)  ? rp[px-1] : 0.f;
        float tr = (px <= 62) ? rp[px+1] : 0.f;
        a += wl*tl + wm*tm + wr*tr;
      }
      if (which == 0) { q[j] = a; sq += a*a; }
      else if (which == 1) { k[j] = a; sk += a*a; }
      else v[j] = a;
    }
  }
  sqq[grp][px] = sq; sqk[grp][px] = sk;
  __syncthreads();
  float tsq = 0.f, tsk = 0.f;
#pragma unroll
  for (int i = 0; i < 8; ++i) { tsq += sqq[i][px]; tsk += sqk[i][px]; }
  float tq = temp[h] * LOG2E / fmaxf(sqrtf(tsq), 1e-12f);
  float ik = 1.f            / fmaxf(sqrtf(tsk), 1e-12f);
  *(uint*)(Qb + ((size_t)bh*HW + n)*16 + grp*2) = cvtpk(q[0]*tq, q[1]*tq);
  *(uint*)(Kb + ((size_t)bh*HW + n)*16 + grp*2) = cvtpk(k[0]*ik, k[1]*ik);
  Vtb[((size_t)bh*16 + grp*2    )*HW + n] = (ushort)(cvtpk(v[0], v[0]) & 0xffffu);
  Vtb[((size_t)bh*16 + grp*2 + 1)*HW + n] = (ushort)(cvtpk(v[1], v[1]) & 0xffffu);
}

// ---------- K3: MFMA flash attention: skewed LDS pipeline + K/V global prefetch ----------
#define PACK(stv, wbp) do {                                              \
  _Pragma("unroll")                                                      \
  for (int g4 = 0; g4 < 4; ++g4) {                                       \
    float e0 = fmaxf(fexp2((stv)[4*g4+0]), 1.f);                         \
    float e1 = fmaxf(fexp2((stv)[4*g4+1]), 1.f);                         \
    float e2 = fmaxf(fexp2((stv)[4*g4+2]), 1.f);                         \
    float e3 = fmaxf(fexp2((stv)[4*g4+3]), 1.f);                         \
    uint2 pk;                                                            \
    pk.x = cvtpk(e0, e1);                                                \
    pk.y = cvtpk(e2, e3);                                                \
    *(uint2*)((wbp) + wroff + 16*(g4 ^ sw)) = pk;                        \
  } } while (0)

__global__ __launch_bounds__(256) void k_attn(const ushort* __restrict__ Qb,
                                              const ushort* __restrict__ Kb,
                                              const ushort* __restrict__ Vtb,
                                              float* __restrict__ part) {
  __shared__ char smem[4][4096];       // per-wave slice
  int blk = blockIdx.x;                // bh(6) x qt(32) x ks(4)
  int ks = blk & (KSPLIT-1);
  int qt = (blk >> 2) & 31;
  int bh = blk >> 7;
  int lane = threadIdx.x & 63;
  int wid  = threadIdx.x >> 6;
  int l31 = lane & 31;
  int lhi = lane >> 5;
  int qbase = qt*128 + wid*32;

  bf16x8 qf = *(const bf16x8*)(Qb + ((size_t)bh*HW + qbase + l31)*16 + lhi*8);

  const f32x16 z16 = {0,0,0,0,0,0,0,0,0,0,0,0,0,0,0,0};
  const short oneb = (short)0x3f80;
  const bf16x8 ones = {oneb,oneb,oneb,oneb,oneb,oneb,oneb,oneb};
  f32x4 acc0 = {0,0,0,0}, acc1 = {0,0,0,0};
  f32x4 accD0 = {0,0,0,0}, accD1 = {0,0,0,0};
  char* base = &smem[wid][0];
  int qr = lane & 15, gr = lane >> 4;
  int rdoff0 = qr*64 + 16*(gr ^ ((qr>>1)&3));
  int sw = (l31 >> 1) & 3;
  int wroff = l31*64 + 8*lhi;

  const ushort* Kbase = Kb + (size_t)bh*HW*16;
  const ushort* Vbase = Vtb + ((size_t)bh*16 + qr)*HW;
  int kbeg = ks * (HW/KSPLIT);
  constexpr int ITERS = (HW/KSPLIT)/32;   // 32

  // prologue: S(0) -> buf0; prefetch K(1) and V(0)
  bf16x8 kf = *(const bf16x8*)(Kbase + (size_t)(kbeg + l31)*16 + lhi*8);
  f32x16 st = __builtin_amdgcn_mfma_f32_32x32x16_bf16(kf, qf, z16, 0, 0, 0);
  bf16x8 kfn = *(const bf16x8*)(Kbase + (size_t)(kbeg + 32 + l31)*16 + lhi*8);
  bf16x8 vfn = *(const bf16x8*)(Vbase + kbeg + 8*gr);
  PACK(st, base);

#pragma unroll 4
  for (int i = 1; i < ITERS; ++i) {
    char* rb = base + ((i-1) & 1)*2048;
    bf16x8 pa0 = *(const bf16x8*)(rb + rdoff0);
    bf16x8 pa1 = *(const bf16x8*)(rb + 1024 + rdoff0);
    f32x16 stn = __builtin_amdgcn_mfma_f32_32x32x16_bf16(kfn, qf, z16, 0, 0, 0);
    // prefetch K(i+1); at i=ITERS-1 reads adjacent ws region, never consumed.
    kfn = *(const bf16x8*)(Kbase + (size_t)(kbeg + (i+1)*32 + l31)*16 + lhi*8);
    bf16x8 vf = vfn;
    vfn = *(const bf16x8*)(Vbase + kbeg + i*32 + 8*gr);   // V(i) for next iter
    acc0  = __builtin_amdgcn_mfma_f32_16x16x32_bf16(pa0, vf, acc0, 0, 0, 0);
    acc1  = __builtin_amdgcn_mfma_f32_16x16x32_bf16(pa1, vf, acc1, 0, 0, 0);
    accD0 = __builtin_amdgcn_mfma_f32_16x16x32_bf16(pa0, ones, accD0, 0, 0, 0);
    accD1 = __builtin_amdgcn_mfma_f32_16x16x32_bf16(pa1, ones, accD1, 0, 0, 0);
    PACK(stn, base + (i & 1)*2048);
  }
  {
    char* rb = base + ((ITERS-1) & 1)*2048;
    bf16x8 pa0 = *(const bf16x8*)(rb + rdoff0);
    bf16x8 pa1 = *(const bf16x8*)(rb + 1024 + rdoff0);
    acc0  = __builtin_amdgcn_mfma_f32_16x16x32_bf16(pa0, vfn, acc0, 0, 0, 0);
    acc1  = __builtin_amdgcn_mfma_f32_16x16x32_bf16(pa1, vfn, acc1, 0, 0, 0);
    accD0 = __builtin_amdgcn_mfma_f32_16x16x32_bf16(pa0, ones, accD0, 0, 0, 0);
    accD1 = __builtin_amdgcn_mfma_f32_16x16x32_bf16(pa1, ones, accD1, 0, 0, 0);
  }

  // epilogue overlay: ep[slot][q] f32 in the wave's own slice
  float* ep = (float*)base;
#pragma unroll
  for (int r = 0; r < 4; ++r) {
    ep[qr*32 + gr*4 + r]      = acc0[r];
    ep[qr*32 + gr*4 + 16 + r] = acc1[r];
  }
  if (qr == 0) {
#pragma unroll
    for (int r = 0; r < 4; ++r) {
      ep[16*32 + gr*4 + r]      = accD0[r];
      ep[16*32 + gr*4 + 16 + r] = accD1[r];
    }
  }
  __syncthreads();
  size_t pb = ((size_t)(ks*6 + bh))*NPLANE;
  for (int i = threadIdx.x; i < 4*32*NPLANE; i += 256) {
    int w = i / (32*NPLANE);
    int rem = i - w*(32*NPLANE);
    int cc = rem >> 5;
    int q = rem & 31;
    part[(pb + cc)*HW + qt*128 + w*32 + q] = ((float*)&smem[w][0])[cc*32 + q];
  }
}

// ---------- K4: tail — SE + ksplit-reduce + combine + LN2 + full FFN ----------
// 128 blocks x 768 thr (12 waves); wave w owns 4 WAVE-UNIFORM channels
// (c0 = w*4 via readfirstlane -> s_load weight rows); 64-px tiles.
__global__ __launch_bounds__(768) void k_tail(const float* __restrict__ part,
                                              const float* __restrict__ x,
                                              const float* __restrict__ lw1,
                                              const float* __restrict__ lb1,
                                              const float* __restrict__ bpool,
                                              const float* __restrict__ w1,
                                              const float* __restrict__ b1,
                                              const float* __restrict__ w2,
                                              const float* __restrict__ b2,
                                              const float* __restrict__ beta,
                                              const float* __restrict__ beta2,
                                              const float* __restrict__ lw2,
                                              const float* __restrict__ lb2,
                                              const float* __restrict__ w4,
                                              const float* __restrict__ b4,
                                              const float* __restrict__ w5,
                                              const float* __restrict__ b5,
                                              const float* __restrict__ gamma,
                                              float* __restrict__ out) {
  __shared__ float sepm[CH][4];
  __shared__ float pmL[CH];
  __shared__ float yrL[4];
  __shared__ float seL[CH];
  __shared__ float r1[12][64], r2[12][64], r3[12][64], r4[12][64];
  __shared__ float xt[CH][65];   // LN2 output
  __shared__ float gt[CH][65];   // gate output
  int t = threadIdx.x;
  int px = t & 63, w = t >> 6;        // 12 waves
  int h = w >> 2;
  int c0 = __builtin_amdgcn_readfirstlane(w * 4);
  int qoff = __builtin_amdgcn_readfirstlane((w & 3) * 4);
  int gp = blockIdx.x*64 + px;
  int b = gp >> 12, n = gp & 4095;
  int bh = b*NH + h;

  // SE MLP (block-redundant; bpool is L2-hot; 64 row-partials per b)
  if (t < 192) {
    int c = t % CH, j = t / CH;       // j 0..3
    const float* bp = bpool + (size_t)(b*64 + j*16)*CH + c;
    float a = 0.f;
#pragma unroll
    for (int i = 0; i < 16; ++i) a += bp[(size_t)i*CH];
    sepm[c][j] = a;
  }
  __syncthreads();
  if (t < CH) pmL[t] = (sepm[t][0]+sepm[t][1]+sepm[t][2]+sepm[t][3]) * (1.f/HW);
  __syncthreads();
  if (t < RR) {
    float a = b1[t];
    for (int c = 0; c < CH; ++c) a += w1[t*CH+c]*pmL[c];
    yrL[t] = fmaxf(a, 0.f);
  }
  __syncthreads();
  if (t < CH) {
    float a = b2[t];
    for (int r = 0; r < RR; ++r) a += w2[t*RR+r]*yrL[r];
    seL[t] = 1.f/(1.f+__expf(-a));
  }

  // ksplit reduce: 4 channels + den per thread
  float acc[4] = {0,0,0,0};
  float den = 0.f;
#pragma unroll
  for (int ks = 0; ks < KSPLIT; ++ks) {
    const float* pl = part + ((size_t)((ks*6+bh)*NPLANE + qoff))*HW + n;
#pragma unroll
    for (int cc = 0; cc < 4; ++cc) acc[cc] += pl[(size_t)cc*HW];
    den += pl[(size_t)(16 - qoff)*HW];
  }
  // LN1 stats on x
  const float* xp = x + ((size_t)b*CH + c0)*HW + n;
  float xv[4]; float s = 0.f, ssum = 0.f;
#pragma unroll
  for (int cc = 0; cc < 4; ++cc) {
    float vv = xp[(size_t)cc*HW];
    xv[cc] = vv; s += vv; ssum += vv*vv;
  }
  r1[w][px] = s; r2[w][px] = ssum;
  __syncthreads();
  float stot = 0.f, sstot = 0.f;
#pragma unroll
  for (int i = 0; i < 12; ++i) { stot += r1[i][px]; sstot += r2[i][px]; }
  float mu = stot*(1.f/CH);
  float rs = rsqrtf(sstot*(1.f/CH) - mu*mu + 1e-6f);
  float inv = 1.f / den;
  float yv[4]; float s2 = 0.f, ss2 = 0.f;
#pragma unroll
  for (int cc = 0; cc < 4; ++cc) {
    int c = c0 + cc;
    float xnv = lw1[c]*((xv[cc]-mu)*rs) + lb1[c];
    float y = xv[cc] + xnv*seL[c]*beta[c] + acc[cc]*inv*beta2[c];
    yv[cc] = y; s2 += y; ss2 += y*y;
  }
  r3[w][px] = s2; r4[w][px] = ss2;
  __syncthreads();
  float s2t = 0.f, ss2t = 0.f;
#pragma unroll
  for (int i = 0; i < 12; ++i) { s2t += r3[i][px]; ss2t += r4[i][px]; }
  float mu2 = s2t*(1.f/CH);
  float rs2 = rsqrtf(ss2t*(1.f/CH) - mu2*mu2 + 1e-6f);
#pragma unroll
  for (int cc = 0; cc < 4; ++cc) {
    int c = c0 + cc;
    xt[c][px] = lw2[c]*((yv[cc]-mu2)*rs2) + lb2[c];
  }
  __syncthreads();

  // conv4 + gate: wave-uniform rows via s_load
  float f1[4], f2[4];
#pragma unroll
  for (int j = 0; j < 4; ++j) { f1[j] = b4[c0+j]; f2[j] = b4[CH+c0+j]; }
#pragma unroll 8
  for (int c = 0; c < CH; ++c) {
    float tc = xt[c][px];
#pragma unroll
    for (int j = 0; j < 4; ++j) {
      f1[j] += w4[(size_t)(c0+j)*CH + c] * tc;
      f2[j] += w4[(size_t)(CH+c0+j)*CH + c] * tc;
    }
  }
#pragma unroll
  for (int j = 0; j < 4; ++j) gt[c0+j][px] = f1[j]*f2[j];
  __syncthreads();

  // conv5 + residual
  float f5[4];
#pragma unroll
  for (int j = 0; j < 4; ++j) f5[j] = b5[c0+j];
#pragma unroll 8
  for (int c = 0; c < CH; ++c) {
    float gc = gt[c][px];
#pragma unroll
    for (int j = 0; j < 4; ++j) f5[j] += w5[(size_t)(c0+j)*CH + c] * gc;
  }
  float* op = out + ((size_t)b*CH + c0)*HW + n;
#pragma unroll
  for (int j = 0; j < 4; ++j)
    op[(size_t)j*HW] = yv[j] + f5[j]*gamma[c0+j];
}

extern "C" void kernel_launch(void* const* d_in, const int* in_sizes, int n_in,
                              void* d_out, int out_size, void* d_ws, size_t ws_size,
                              hipStream_t stream) {
  const float* x      = (const float*)d_in[0];
  const float* ln1_w  = (const float*)d_in[1];
  const float* ln1_b  = (const float*)d_in[2];
  const float* qkv_w  = (const float*)d_in[3];
  const float* qkv_b  = (const float*)d_in[4];
  const float* dw_w   = (const float*)d_in[5];
  const float* dw_b   = (const float*)d_in[6];
  const float* temp   = (const float*)d_in[7];
  const float* ca_w1  = (const float*)d_in[8];
  const float* ca_b1  = (const float*)d_in[9];
  const float* ca_w2  = (const float*)d_in[10];
  const float* ca_b2  = (const float*)d_in[11];
  const float* beta   = (const float*)d_in[12];
  const float* beta2  = (const float*)d_in[13];
  const float* ln2_w  = (const float*)d_in[14];
  const float* ln2_b  = (const float*)d_in[15];
  const float* conv4_w= (const float*)d_in[16];
  const float* conv4_b= (const float*)d_in[17];
  const float* conv5_w= (const float*)d_in[18];
  const float* conv5_b= (const float*)d_in[19];
  const float* gamma  = (const float*)d_in[20];

  float* ws   = (float*)d_ws;
  float* bp   = ws + OFF_BP;
  ushort* Qb  = (ushort*)(ws + OFF_QB);
  ushort* Kb  = (ushort*)(ws + OFF_KB);
  ushort* Vtb = (ushort*)(ws + OFF_VT);
  float* qkv1 = ws + OFF_QKV1;
  float* part = ws + OFF_PART;
  float* out  = (float*)d_out;

  k_lnconv<<<256, 512, 0, stream>>>(x, ln1_w, ln1_b, qkv_w, qkv_b, qkv1, bp);
  k_dwprep<<<384, 512, 0, stream>>>(qkv1, dw_w, dw_b, temp, Qb, Kb, Vtb);
  k_attn  <<<768, 256, 0, stream>>>(Qb, Kb, Vtb, part);
  k_tail  <<<128, 768, 0, stream>>>(part, x, ln1_w, ln1_b, bp,
                                    ca_w1, ca_b1, ca_w2, ca_b2,
                                    beta, beta2, ln2_w, ln2_b,
                                    conv4_w, conv4_b, conv5_w, conv5_b,
                                    gamma, out);
}

// Round 13
// 52.465 us; speedup vs baseline: 1.4007x; 1.0903x over previous
//
#include <hip/hip_runtime.h>
#include <cstddef>
#include <cmath>

#define BN 2
#define CH 48
#define HW 4096
#define NH 3
#define QC 144      // 3*CH
#define RR 3        // CH/16
#define KSPLIT 4
#define NPLANE 17   // 16 acc + 1 denom planes per (ks,bh)
#define LOG2E 1.4426950408889634f

typedef __attribute__((ext_vector_type(8))) short bf16x8;
typedef __attribute__((ext_vector_type(16))) float f32x16;
typedef __attribute__((ext_vector_type(4))) float f32x4;

// ---- workspace layout (floats) ----
constexpr size_t OFF_BP  = 0;                       // 128*48 rows (b*64+row)
constexpr size_t OFF_QB  = 12288;                   // 98304 (bf16 [bh][n][16])
constexpr size_t OFF_KB  = OFF_QB + 98304;
constexpr size_t OFF_VT  = OFF_KB + 98304;
constexpr size_t OFF_PART= OFF_VT + 98304 + 1179648; // 4*6*17*4096 = 1671168

static __device__ __forceinline__ unsigned cvtpk(float lo, float hi) {
  unsigned r;
  asm("v_cvt_pk_bf16_f32 %0, %1, %2" : "=v"(r) : "v"(lo), "v"(hi));
  return r;
}

static __device__ __forceinline__ float fexp2(float x) {
#if __has_builtin(__builtin_amdgcn_exp2f)
  return __builtin_amdgcn_exp2f(x);
#else
  float r; asm("v_exp_f32 %0, %1" : "=v"(r) : "v"(x)); return r;
#endif
}

// ---------- K1: fused LN1 + conv1x1 + depthwise3x3 + token norm/pack ----------
// Block = (bh, image row), 512 thr = 8 waves. Recomputes LN+conv for the 3
// stencil rows in LDS; qkv1 never touches HBM. ALL weight-row indices are
// readfirstlane'd -> s_load SGPR broadcasts (the R11 k_front lacked this and
// was VMEM-stall-bound at 39us). OOB halo rows zeroed (SAME-pad -> exact).
__global__ __launch_bounds__(512) void k_front(const float* __restrict__ x,
                                               const float* __restrict__ lw,
                                               const float* __restrict__ lb,
                                               const float* __restrict__ w,
                                               const float* __restrict__ bias,
                                               const float* __restrict__ dww,
                                               const float* __restrict__ dwb,
                                               const float* __restrict__ temp,
                                               ushort* __restrict__ Qb,
                                               ushort* __restrict__ Kb,
                                               ushort* __restrict__ Vtb,
                                               float* __restrict__ bpool) {
  __shared__ float xt1[CH][64];          // LN output, one row at a time
  __shared__ float qt[3][CH][64];        // conv1x1 outputs (oc = which*16+cc)
  __shared__ float red1[8][64], red2[8][64];
  int blk = blockIdx.x;                  // bh*64 + row
  int row = blk & 63, bh = blk >> 6;
  int b = bh / NH, h = bh % NH;
  int t = threadIdx.x;
  int px = t & 63, grp = t >> 6;         // grp 0..7 (= wave id)

  for (int r = 0; r < 3; ++r) {
    int yy = row + r - 1;
    if (yy < 0 || yy >= 64) {            // block-uniform branch
      for (int i = t; i < CH*64; i += 512) (&qt[r][0][0])[i] = 0.f;
      __syncthreads();
      continue;
    }
    // LN phase: wave grp loads 6 channels of this row
    const float* xb = x + (size_t)b*CH*HW + yy*64 + px;
    float v[6]; float s = 0.f, ss = 0.f;
#pragma unroll
    for (int j = 0; j < 6; ++j) {
      float vv = xb[(size_t)(grp*6 + j)*HW];
      v[j] = vv; s += vv; ss += vv*vv;
    }
    red1[grp][px] = s; red2[grp][px] = ss;
    __syncthreads();
    float stot = 0.f, sstot = 0.f;
#pragma unroll
    for (int i = 0; i < 8; ++i) { stot += red1[i][px]; sstot += red2[i][px]; }
    float mu = stot * (1.f/CH);
    float rs = rsqrtf(sstot*(1.f/CH) - mu*mu + 1e-6f);
#pragma unroll
    for (int j = 0; j < 6; ++j) {
      int c = grp*6 + j;
      xt1[c][px] = lw[c]*((v[j]-mu)*rs) + lb[c];
    }
    __syncthreads();
    // per-row pool partial (h==0 blocks, center row only)
    if (r == 1 && h == 0 && t < CH) {
      float a = 0.f;
#pragma unroll
      for (int p2 = 0; p2 < 64; ++p2) a += xt1[t][p2];
      bpool[(size_t)(b*64 + row)*CH + t] = a;
    }
    // conv phase: wave grp computes oc = grp*6..+5 (weights via s_load)
    float xv[CH];
#pragma unroll
    for (int ci = 0; ci < CH; ++ci) xv[ci] = xt1[ci][px];
#pragma unroll
    for (int oi = 0; oi < 6; ++oi) {
      int oc = grp*6 + oi;
      int c = __builtin_amdgcn_readfirstlane((oc >> 4)*48 + h*16 + (oc & 15));
      const float* wrow = w + (size_t)c*CH;
      float a = bias[c];
#pragma unroll
      for (int ci = 0; ci < CH; ++ci) a += wrow[ci]*xv[ci];
      qt[r][oc][px] = a;
    }
    __syncthreads();
  }

  // depthwise 3x3 (rows in LDS) + norms + pack; weights via s_load
  int n = row*64 + px;
  float q[2], k[2], vv2[2];
  float sq = 0.f, sk = 0.f;
#pragma unroll
  for (int j = 0; j < 2; ++j) {
    int cc = grp*2 + j;
#pragma unroll
    for (int which = 0; which < 3; ++which) {
      int oc = which*16 + cc;
      int cg = __builtin_amdgcn_readfirstlane(which*48 + h*16 + cc);
      const float* wc = dww + (size_t)cg*9;
      float w0 = wc[0], w1 = wc[1], w2 = wc[2],
            w3 = wc[3], w4 = wc[4], w5 = wc[5],
            w6 = wc[6], w7 = wc[7], w8 = wc[8];
      float a = dwb[cg];
#pragma unroll
      for (int rr = 0; rr < 3; ++rr) {
        float wl = rr==0?w0:(rr==1?w3:w6);
        float wm = rr==0?w1:(rr==1?w4:w7);
        float wr = rr==0?w2:(rr==1?w5:w8);
        float tm = qt[rr][oc][px];
        float tl = (px >= 1)  ? qt[rr][oc][px-1] : 0.f;
        float tr = (px <= 62) ? qt[rr][oc][px+1] : 0.f;
        a += wl*tl + wm*tm + wr*tr;
      }
      if (which == 0)      { q[j] = a;  sq += a*a; }
      else if (which == 1) { k[j] = a;  sk += a*a; }
      else                 vv2[j] = a;
    }
  }
  red1[grp][px] = sq; red2[grp][px] = sk;
  __syncthreads();
  float tsq = 0.f, tsk = 0.f;
#pragma unroll
  for (int i = 0; i < 8; ++i) { tsq += red1[i][px]; tsk += red2[i][px]; }
  float tq = temp[h] * LOG2E / fmaxf(sqrtf(tsq), 1e-12f);
  float ik = 1.f            / fmaxf(sqrtf(tsk), 1e-12f);
  *(uint*)(Qb + ((size_t)bh*HW + n)*16 + grp*2) = cvtpk(q[0]*tq, q[1]*tq);
  *(uint*)(Kb + ((size_t)bh*HW + n)*16 + grp*2) = cvtpk(k[0]*ik, k[1]*ik);
  Vtb[((size_t)bh*16 + grp*2    )*HW + n] = (ushort)(cvtpk(vv2[0], vv2[0]) & 0xffffu);
  Vtb[((size_t)bh*16 + grp*2 + 1)*HW + n] = (ushort)(cvtpk(vv2[1], vv2[1]) & 0xffffu);
}

// ---------- K2: MFMA flash attention: skewed LDS pipeline + K/V prefetch + setprio ----------
#define PACK(stv, wbp) do {                                              \
  _Pragma("unroll")                                                      \
  for (int g4 = 0; g4 < 4; ++g4) {                                       \
    float e0 = fmaxf(fexp2((stv)[4*g4+0]), 1.f);                         \
    float e1 = fmaxf(fexp2((stv)[4*g4+1]), 1.f);                         \
    float e2 = fmaxf(fexp2((stv)[4*g4+2]), 1.f);                         \
    float e3 = fmaxf(fexp2((stv)[4*g4+3]), 1.f);                         \
    uint2 pk;                                                            \
    pk.x = cvtpk(e0, e1);                                                \
    pk.y = cvtpk(e2, e3);                                                \
    *(uint2*)((wbp) + wroff + 16*(g4 ^ sw)) = pk;                        \
  } } while (0)

__global__ __launch_bounds__(256) void k_attn(const ushort* __restrict__ Qb,
                                              const ushort* __restrict__ Kb,
                                              const ushort* __restrict__ Vtb,
                                              float* __restrict__ part) {
  __shared__ char smem[4][4096];       // per-wave slice
  int blk = blockIdx.x;                // bh(6) x qt(32) x ks(4)
  int ks = blk & (KSPLIT-1);
  int qt = (blk >> 2) & 31;
  int bh = blk >> 7;
  int lane = threadIdx.x & 63;
  int wid  = threadIdx.x >> 6;
  int l31 = lane & 31;
  int lhi = lane >> 5;
  int qbase = qt*128 + wid*32;

  bf16x8 qf = *(const bf16x8*)(Qb + ((size_t)bh*HW + qbase + l31)*16 + lhi*8);

  const f32x16 z16 = {0,0,0,0,0,0,0,0,0,0,0,0,0,0,0,0};
  const short oneb = (short)0x3f80;
  const bf16x8 ones = {oneb,oneb,oneb,oneb,oneb,oneb,oneb,oneb};
  f32x4 acc0 = {0,0,0,0}, acc1 = {0,0,0,0};
  f32x4 accD0 = {0,0,0,0}, accD1 = {0,0,0,0};
  char* base = &smem[wid][0];
  int qr = lane & 15, gr = lane >> 4;
  int rdoff0 = qr*64 + 16*(gr ^ ((qr>>1)&3));
  int sw = (l31 >> 1) & 3;
  int wroff = l31*64 + 8*lhi;

  const ushort* Kbase = Kb + (size_t)bh*HW*16;
  const ushort* Vbase = Vtb + ((size_t)bh*16 + qr)*HW;
  int kbeg = ks * (HW/KSPLIT);
  constexpr int ITERS = (HW/KSPLIT)/32;   // 32

  // prologue: S(0) -> buf0; prefetch K(1) and V(0)
  bf16x8 kf = *(const bf16x8*)(Kbase + (size_t)(kbeg + l31)*16 + lhi*8);
  f32x16 st = __builtin_amdgcn_mfma_f32_32x32x16_bf16(kf, qf, z16, 0, 0, 0);
  bf16x8 kfn = *(const bf16x8*)(Kbase + (size_t)(kbeg + 32 + l31)*16 + lhi*8);
  bf16x8 vfn = *(const bf16x8*)(Vbase + kbeg + 8*gr);
  PACK(st, base);

#pragma unroll 4
  for (int i = 1; i < ITERS; ++i) {
    char* rb = base + ((i-1) & 1)*2048;
    bf16x8 pa0 = *(const bf16x8*)(rb + rdoff0);
    bf16x8 pa1 = *(const bf16x8*)(rb + 1024 + rdoff0);
    __builtin_amdgcn_s_setprio(1);
    f32x16 stn = __builtin_amdgcn_mfma_f32_32x32x16_bf16(kfn, qf, z16, 0, 0, 0);
    // prefetch K(i+1); at i=ITERS-1 reads adjacent ws region, never consumed.
    kfn = *(const bf16x8*)(Kbase + (size_t)(kbeg + (i+1)*32 + l31)*16 + lhi*8);
    bf16x8 vf = vfn;
    vfn = *(const bf16x8*)(Vbase + kbeg + i*32 + 8*gr);   // V(i) for next iter
    acc0  = __builtin_amdgcn_mfma_f32_16x16x32_bf16(pa0, vf, acc0, 0, 0, 0);
    acc1  = __builtin_amdgcn_mfma_f32_16x16x32_bf16(pa1, vf, acc1, 0, 0, 0);
    accD0 = __builtin_amdgcn_mfma_f32_16x16x32_bf16(pa0, ones, accD0, 0, 0, 0);
    accD1 = __builtin_amdgcn_mfma_f32_16x16x32_bf16(pa1, ones, accD1, 0, 0, 0);
    __builtin_amdgcn_s_setprio(0);
    PACK(stn, base + (i & 1)*2048);
  }
  {
    char* rb = base + ((ITERS-1) & 1)*2048;
    bf16x8 pa0 = *(const bf16x8*)(rb + rdoff0);
    bf16x8 pa1 = *(const bf16x8*)(rb + 1024 + rdoff0);
    acc0  = __builtin_amdgcn_mfma_f32_16x16x32_bf16(pa0, vfn, acc0, 0, 0, 0);
    acc1  = __builtin_amdgcn_mfma_f32_16x16x32_bf16(pa1, vfn, acc1, 0, 0, 0);
    accD0 = __builtin_amdgcn_mfma_f32_16x16x32_bf16(pa0, ones, accD0, 0, 0, 0);
    accD1 = __builtin_amdgcn_mfma_f32_16x16x32_bf16(pa1, ones, accD1, 0, 0, 0);
  }

  // epilogue overlay: ep[slot][q] f32 in the wave's own slice
  float* ep = (float*)base;
#pragma unroll
  for (int r = 0; r < 4; ++r) {
    ep[qr*32 + gr*4 + r]      = acc0[r];
    ep[qr*32 + gr*4 + 16 + r] = acc1[r];
  }
  if (qr == 0) {
#pragma unroll
    for (int r = 0; r < 4; ++r) {
      ep[16*32 + gr*4 + r]      = accD0[r];
      ep[16*32 + gr*4 + 16 + r] = accD1[r];
    }
  }
  __syncthreads();
  size_t pb = ((size_t)(ks*6 + bh))*NPLANE;
  for (int i = threadIdx.x; i < 4*32*NPLANE; i += 256) {
    int w = i / (32*NPLANE);
    int rem = i - w*(32*NPLANE);
    int cc = rem >> 5;
    int q = rem & 31;
    part[(pb + cc)*HW + qt*128 + w*32 + q] = ((float*)&smem[w][0])[cc*32 + q];
  }
}

// ---------- K3: tail — SE + ksplit-reduce + combine + LN2 + full FFN ----------
// 128 blocks x 768 thr (12 waves); wave w owns 4 WAVE-UNIFORM channels.
__global__ __launch_bounds__(768) void k_tail(const float* __restrict__ part,
                                              const float* __restrict__ x,
                                              const float* __restrict__ lw1,
                                              const float* __restrict__ lb1,
                                              const float* __restrict__ bpool,
                                              const float* __restrict__ w1,
                                              const float* __restrict__ b1,
                                              const float* __restrict__ w2,
                                              const float* __restrict__ b2,
                                              const float* __restrict__ beta,
                                              const float* __restrict__ beta2,
                                              const float* __restrict__ lw2,
                                              const float* __restrict__ lb2,
                                              const float* __restrict__ w4,
                                              const float* __restrict__ b4,
                                              const float* __restrict__ w5,
                                              const float* __restrict__ b5,
                                              const float* __restrict__ gamma,
                                              float* __restrict__ out) {
  __shared__ float sepm[CH][4];
  __shared__ float pmL[CH];
  __shared__ float yrL[4];
  __shared__ float seL[CH];
  __shared__ float r1[12][64], r2[12][64], r3[12][64], r4[12][64];
  __shared__ float xt[CH][65];   // LN2 output
  __shared__ float gt[CH][65];   // gate output
  int t = threadIdx.x;
  int px = t & 63, w = t >> 6;        // 12 waves
  int h = w >> 2;
  int c0 = __builtin_amdgcn_readfirstlane(w * 4);
  int qoff = __builtin_amdgcn_readfirstlane((w & 3) * 4);
  int gp = blockIdx.x*64 + px;
  int b = gp >> 12, n = gp & 4095;
  int bh = b*NH + h;

  // SE MLP (block-redundant; bpool is L2-hot; 64 row-partials per b)
  if (t < 192) {
    int c = t % CH, j = t / CH;       // j 0..3
    const float* bp = bpool + (size_t)(b*64 + j*16)*CH + c;
    float a = 0.f;
#pragma unroll
    for (int i = 0; i < 16; ++i) a += bp[(size_t)i*CH];
    sepm[c][j] = a;
  }
  __syncthreads();
  if (t < CH) pmL[t] = (sepm[t][0]+sepm[t][1]+sepm[t][2]+sepm[t][3]) * (1.f/HW);
  __syncthreads();
  if (t < RR) {
    float a = b1[t];
    for (int c = 0; c < CH; ++c) a += w1[t*CH+c]*pmL[c];
    yrL[t] = fmaxf(a, 0.f);
  }
  __syncthreads();
  if (t < CH) {
    float a = b2[t];
    for (int r = 0; r < RR; ++r) a += w2[t*RR+r]*yrL[r];
    seL[t] = 1.f/(1.f+__expf(-a));
  }

  // ksplit reduce: 4 channels + den per thread
  float acc[4] = {0,0,0,0};
  float den = 0.f;
#pragma unroll
  for (int ks = 0; ks < KSPLIT; ++ks) {
    const float* pl = part + ((size_t)((ks*6+bh)*NPLANE + qoff))*HW + n;
#pragma unroll
    for (int cc = 0; cc < 4; ++cc) acc[cc] += pl[(size_t)cc*HW];
    den += pl[(size_t)(16 - qoff)*HW];
  }
  // LN1 stats on x
  const float* xp = x + ((size_t)b*CH + c0)*HW + n;
  float xv[4]; float s = 0.f, ssum = 0.f;
#pragma unroll
  for (int cc = 0; cc < 4; ++cc) {
    float vv = xp[(size_t)cc*HW];
    xv[cc] = vv; s += vv; ssum += vv*vv;
  }
  r1[w][px] = s; r2[w][px] = ssum;
  __syncthreads();
  float stot = 0.f, sstot = 0.f;
#pragma unroll
  for (int i = 0; i < 12; ++i) { stot += r1[i][px]; sstot += r2[i][px]; }
  float mu = stot*(1.f/CH);
  float rs = rsqrtf(sstot*(1.f/CH) - mu*mu + 1e-6f);
  float inv = 1.f / den;
  float yv[4]; float s2 = 0.f, ss2 = 0.f;
#pragma unroll
  for (int cc = 0; cc < 4; ++cc) {
    int c = c0 + cc;
    float xnv = lw1[c]*((xv[cc]-mu)*rs) + lb1[c];
    float y = xv[cc] + xnv*seL[c]*beta[c] + acc[cc]*inv*beta2[c];
    yv[cc] = y; s2 += y; ss2 += y*y;
  }
  r3[w][px] = s2; r4[w][px] = ss2;
  __syncthreads();
  float s2t = 0.f, ss2t = 0.f;
#pragma unroll
  for (int i = 0; i < 12; ++i) { s2t += r3[i][px]; ss2t += r4[i][px]; }
  float mu2 = s2t*(1.f/CH);
  float rs2 = rsqrtf(ss2t*(1.f/CH) - mu2*mu2 + 1e-6f);
#pragma unroll
  for (int cc = 0; cc < 4; ++cc) {
    int c = c0 + cc;
    xt[c][px] = lw2[c]*((yv[cc]-mu2)*rs2) + lb2[c];
  }
  __syncthreads();

  // conv4 + gate: wave-uniform rows via s_load
  float f1[4], f2[4];
#pragma unroll
  for (int j = 0; j < 4; ++j) { f1[j] = b4[c0+j]; f2[j] = b4[CH+c0+j]; }
#pragma unroll 8
  for (int c = 0; c < CH; ++c) {
    float tc = xt[c][px];
#pragma unroll
    for (int j = 0; j < 4; ++j) {
      f1[j] += w4[(size_t)(c0+j)*CH + c] * tc;
      f2[j] += w4[(size_t)(CH+c0+j)*CH + c] * tc;
    }
  }
#pragma unroll
  for (int j = 0; j < 4; ++j) gt[c0+j][px] = f1[j]*f2[j];
  __syncthreads();

  // conv5 + residual
  float f5[4];
#pragma unroll
  for (int j = 0; j < 4; ++j) f5[j] = b5[c0+j];
#pragma unroll 8
  for (int c = 0; c < CH; ++c) {
    float gc = gt[c][px];
#pragma unroll
    for (int j = 0; j < 4; ++j) f5[j] += w5[(size_t)(c0+j)*CH + c] * gc;
  }
  float* op = out + ((size_t)b*CH + c0)*HW + n;
#pragma unroll
  for (int j = 0; j < 4; ++j)
    op[(size_t)j*HW] = yv[j] + f5[j]*gamma[c0+j];
}

extern "C" void kernel_launch(void* const* d_in, const int* in_sizes, int n_in,
                              void* d_out, int out_size, void* d_ws, size_t ws_size,
                              hipStream_t stream) {
  const float* x      = (const float*)d_in[0];
  const float* ln1_w  = (const float*)d_in[1];
  const float* ln1_b  = (const float*)d_in[2];
  const float* qkv_w  = (const float*)d_in[3];
  const float* qkv_b  = (const float*)d_in[4];
  const float* dw_w   = (const float*)d_in[5];
  const float* dw_b   = (const float*)d_in[6];
  const float* temp   = (const float*)d_in[7];
  const float* ca_w1  = (const float*)d_in[8];
  const float* ca_b1  = (const float*)d_in[9];
  const float* ca_w2  = (const float*)d_in[10];
  const float* ca_b2  = (const float*)d_in[11];
  const float* beta   = (const float*)d_in[12];
  const float* beta2  = (const float*)d_in[13];
  const float* ln2_w  = (const float*)d_in[14];
  const float* ln2_b  = (const float*)d_in[15];
  const float* conv4_w= (const float*)d_in[16];
  const float* conv4_b= (const float*)d_in[17];
  const float* conv5_w= (const float*)d_in[18];
  const float* conv5_b= (const float*)d_in[19];
  const float* gamma  = (const float*)d_in[20];

  float* ws   = (float*)d_ws;
  float* bp   = ws + OFF_BP;
  ushort* Qb  = (ushort*)(ws + OFF_QB);
  ushort* Kb  = (ushort*)(ws + OFF_KB);
  ushort* Vtb = (ushort*)(ws + OFF_VT);
  float* part = ws + OFF_PART;
  float* out  = (float*)d_out;

  k_front<<<384, 512, 0, stream>>>(x, ln1_w, ln1_b, qkv_w, qkv_b,
                                   dw_w, dw_b, temp, Qb, Kb, Vtb, bp);
  k_attn <<<768, 256, 0, stream>>>(Qb, Kb, Vtb, part);
  k_tail <<<128, 768, 0, stream>>>(part, x, ln1_w, ln1_b, bp,
                                   ca_w1, ca_b1, ca_w2, ca_b2,
                                   beta, beta2, ln2_w, ln2_b,
                                   conv4_w, conv4_b, conv5_w, conv5_b,
                                   gamma, out);
}